// Round 1
// baseline (1055.892 us; speedup 1.0000x reference)
//
#include <hip/hip_runtime.h>
#include <math.h>

typedef unsigned short u16;
typedef unsigned int u32;
typedef __attribute__((ext_vector_type(8))) __bf16 bf16x8;
typedef __attribute__((ext_vector_type(4))) float f32x4;
typedef __attribute__((ext_vector_type(8))) u16 u16x8;
typedef __attribute__((ext_vector_type(4))) u16 u16x4;

#define BB 2
#define SS 2048
#define HH 2048
#define NHH 16
#define DD 128
#define FFF 8192
#define MM (BB * SS)

__device__ __forceinline__ u16 f2bf(float f) {
  u32 u = __float_as_uint(f);
  u32 r = (u + 0x7FFFu + ((u >> 16) & 1u)) >> 16;
  return (u16)r;
}
__device__ __forceinline__ float b2f(u16 h) {
  return __uint_as_float(((u32)h) << 16);
}
__device__ __forceinline__ void gll16(const void* g, void* l) {
  __builtin_amdgcn_global_load_lds((const __attribute__((address_space(1))) void*)g,
                                   (__attribute__((address_space(3))) void*)l, 16, 0, 0);
}

// ---------------- batched fp32 -> bf16 convert (all 4 weight mats, 1 launch) ----------------
struct CvtArgs {
  const float* src[4];
  u16* dst[4];
  int n[4];
};
__global__ __launch_bounds__(256) void cvt_all(CvtArgs a) {
  const int seg = blockIdx.y;
  const int i = (blockIdx.x * 256 + threadIdx.x) * 4;
  if (i + 3 < a.n[seg]) {
    f32x4 v = *(const f32x4*)(a.src[seg] + i);
    u16x4 o;
    o[0] = f2bf(v[0]); o[1] = f2bf(v[1]); o[2] = f2bf(v[2]); o[3] = f2bf(v[3]);
    *(u16x4*)(a.dst[seg] + i) = o;
  }
}

// ---------------- LayerNorm (fp32 in, bf16 out) ----------------
__global__ __launch_bounds__(256) void ln_bf16(const float* __restrict__ x,
                                               const float* __restrict__ w,
                                               const float* __restrict__ bsh,
                                               u16* __restrict__ out) {
  const int row = blockIdx.x, tid = threadIdx.x;
  const float* xr = x + (size_t)row * HH;
  f32x4 a = ((const f32x4*)xr)[tid * 2];
  f32x4 b = ((const f32x4*)xr)[tid * 2 + 1];
  float s = a[0] + a[1] + a[2] + a[3] + b[0] + b[1] + b[2] + b[3];
  float q = a[0]*a[0] + a[1]*a[1] + a[2]*a[2] + a[3]*a[3]
          + b[0]*b[0] + b[1]*b[1] + b[2]*b[2] + b[3]*b[3];
#pragma unroll
  for (int off = 32; off > 0; off >>= 1) {
    s += __shfl_down(s, off);
    q += __shfl_down(q, off);
  }
  __shared__ float red[8];
  const int wave = tid >> 6;
  if ((tid & 63) == 0) { red[wave] = s; red[4 + wave] = q; }
  __syncthreads();
  s = red[0] + red[1] + red[2] + red[3];
  q = red[4] + red[5] + red[6] + red[7];
  const float mean = s * (1.0f / HH);
  const float var = q * (1.0f / HH) - mean * mean;
  const float rstd = 1.0f / sqrtf(var + 1e-5f);
  f32x4 w0 = ((const f32x4*)w)[tid * 2];
  f32x4 w1 = ((const f32x4*)w)[tid * 2 + 1];
  f32x4 b0 = ((const f32x4*)bsh)[tid * 2];
  f32x4 b1 = ((const f32x4*)bsh)[tid * 2 + 1];
  u16x8 o;
#pragma unroll
  for (int i = 0; i < 4; ++i) o[i] = f2bf((a[i] - mean) * rstd * w0[i] + b0[i]);
#pragma unroll
  for (int i = 0; i < 4; ++i) o[4 + i] = f2bf((b[i] - mean) * rstd * w1[i] + b1[i]);
  *(u16x8*)(out + (size_t)row * HH + tid * 8) = o;
}

// ---------------- GEMM 128x128 (kept for N=2048 GEMMs: grid stays 512 blocks) ----------------
// MODE 0: +bias -> bf16.  MODE 1: +bias+resid(f32) -> f32.  MODE 2: +bias, gelu -> bf16.
template <int MODE, int DB>
__global__ __launch_bounds__(256) void gemm_bt(const u16* __restrict__ A,
                                               const u16* __restrict__ Bw,
                                               const float* __restrict__ bias,
                                               const float* resid, void* Cout,
                                               int M, int N, int K) {
  __shared__ __align__(16) u16 As[DB ? 2 : 1][128 * 64];
  __shared__ __align__(16) u16 Bs[DB ? 2 : 1][128 * 64];
  const int tid = threadIdx.x;
  const int wave = tid >> 6, lane = tid & 63;
  const int l15 = lane & 15, quad = lane >> 4;
  const int bm = blockIdx.x, bn = blockIdx.y;
  const int wm = (wave >> 1) << 6, wn = (wave & 1) << 6;

  f32x4 acc[4][4] = {};

  const int srow = (wave << 5) + (lane >> 3);
  const int sg = (lane & 7) ^ (lane >> 3);
  const u16* aptr = A + (size_t)(bm * 128 + srow) * K + sg * 8;
  const u16* bptr = Bw + (size_t)(bn * 128 + srow) * K + sg * 8;

  auto stage = [&](int buf) {
#pragma unroll
    for (int i = 0; i < 4; ++i)
      gll16(aptr + (size_t)i * 8 * K, &As[buf][(wave * 4 + i) * 512]);
#pragma unroll
    for (int i = 0; i < 4; ++i)
      gll16(bptr + (size_t)i * 8 * K, &Bs[buf][(wave * 4 + i) * 512]);
    aptr += 64; bptr += 64;
  };

  auto compute = [&](int buf) {
#pragma unroll
    for (int tt = 0; tt < 2; ++tt) {
      bf16x8 af[4], bfv[4];
#pragma unroll
      for (int i = 0; i < 4; ++i) {
        const int m = wm + i * 16 + l15;
        const int n = wn + i * 16 + l15;
        const int gi = tt * 4 + quad;
        af[i] = *(const bf16x8*)&As[buf][m * 64 + ((gi ^ (m & 7)) << 3)];
        bfv[i] = *(const bf16x8*)&Bs[buf][n * 64 + ((gi ^ (n & 7)) << 3)];
      }
#pragma unroll
      for (int i = 0; i < 4; ++i)
#pragma unroll
        for (int j = 0; j < 4; ++j)
          acc[i][j] = __builtin_amdgcn_mfma_f32_16x16x32_bf16(af[i], bfv[j], acc[i][j], 0, 0, 0);
    }
  };

  const int nk = K >> 6;
  if constexpr (DB) {
    stage(0);
    for (int kt = 0; kt < nk; ++kt) {
      __syncthreads();
      if (kt + 1 < nk) stage((kt + 1) & 1);
      compute(kt & 1);
    }
  } else {
    for (int kt = 0; kt < nk; ++kt) {
      stage(0);
      __syncthreads();
      compute(0);
      __syncthreads();
    }
  }

#pragma unroll
  for (int i = 0; i < 4; ++i) {
    const int row0 = bm * 128 + wm + i * 16 + quad * 4;
#pragma unroll
    for (int j = 0; j < 4; ++j) {
      const int col = bn * 128 + wn + j * 16 + l15;
      const float bv = bias[col];
#pragma unroll
      for (int r = 0; r < 4; ++r) {
        const size_t idx = (size_t)(row0 + r) * N + col;
        float v = acc[i][j][r] + bv;
        if constexpr (MODE == 0) {
          ((u16*)Cout)[idx] = f2bf(v);
        } else if constexpr (MODE == 1) {
          ((float*)Cout)[idx] = v + resid[idx];
        } else {
          v = 0.5f * v * (1.0f + erff(v * 0.70710678118654752f));
          ((u16*)Cout)[idx] = f2bf(v);
        }
      }
    }
  }
}

// ---------------- GEMM 256x256, 8-phase counted-vmcnt schedule (T2+T3+T4+T5) ----------------
// 8 waves (2M x 4N), BK=64, 128 KiB LDS double-buffer.  Per K-tile: 4 phases, each computes one
// C-quadrant (K=64, 16 MFMA) and stages one half-tile of the NEXT tile into the dead buffer.
// Quadrant read order (qm,qn): (0,0)(1,0)(1,1)(0,1); stage order A0,B0,A1,B1 -> every region
// lands >=3 phases before first use; vmcnt(4) (never 0) covers exactly what the next phase reads.
// A-half h = rows {h*64..h*64+63} u {128+h*64..}; B-half h = n-rows {q*64+h*32..+31, q=0..3}.
#define PHASE256(QM, QN, STG, DW)                                                              \
  do {                                                                                         \
    bf16x8 af[4][2], bq[2][2];                                                                 \
    _Pragma("unroll") for (int im = 0; im < 4; ++im) {                                         \
      const int ar = wm * 128 + (QM) * 64 + im * 16 + l15;                                     \
      _Pragma("unroll") for (int tt = 0; tt < 2; ++tt)                                         \
          af[im][tt] = *(const bf16x8*)&as[ar * 64 + ((((tt << 2) + quad) ^ (ar & 7)) << 3)];  \
    }                                                                                          \
    _Pragma("unroll") for (int jn = 0; jn < 2; ++jn) {                                         \
      const int br = wn * 64 + (QN) * 32 + jn * 16 + l15;                                      \
      _Pragma("unroll") for (int tt = 0; tt < 2; ++tt)                                         \
          bq[jn][tt] = *(const bf16x8*)&bs[br * 64 + ((((tt << 2) + quad) ^ (br & 7)) << 3)];  \
    }                                                                                          \
    STG;                                                                                       \
    __builtin_amdgcn_s_barrier();                                                              \
    asm volatile("s_waitcnt lgkmcnt(0)" ::: "memory");                                         \
    __builtin_amdgcn_sched_barrier(0);                                                         \
    __builtin_amdgcn_s_setprio(1);                                                             \
    _Pragma("unroll") for (int tt = 0; tt < 2; ++tt)                                           \
        _Pragma("unroll") for (int im = 0; im < 4; ++im)                                       \
            _Pragma("unroll") for (int jn = 0; jn < 2; ++jn)                                   \
                acc[(QM) * 4 + im][(QN) * 2 + jn] = __builtin_amdgcn_mfma_f32_16x16x32_bf16(   \
                    af[im][tt], bq[jn][tt], acc[(QM) * 4 + im][(QN) * 2 + jn], 0, 0, 0);       \
    __builtin_amdgcn_s_setprio(0);                                                             \
    if (DW) {                                                                                  \
      asm volatile("s_waitcnt vmcnt(4)" ::: "memory");                                         \
      __builtin_amdgcn_sched_barrier(0);                                                       \
    }                                                                                          \
    __builtin_amdgcn_s_barrier();                                                              \
  } while (0)

template <int MODE>
__global__ __launch_bounds__(512, 2) void gemm256(const u16* __restrict__ A,
                                                  const u16* __restrict__ Bw,
                                                  const float* __restrict__ bias,
                                                  void* Cout, int M, int N, int K) {
  __shared__ __align__(16) u16 As[2][256 * 64];
  __shared__ __align__(16) u16 Bs[2][256 * 64];
  const int tid = threadIdx.x;
  const int wave = tid >> 6, lane = tid & 63;
  const int l15 = lane & 15, quad = lane >> 4;
  const int wm = wave >> 2, wn = wave & 3;
  const int bm = blockIdx.x, bn = blockIdx.y;

  f32x4 acc[8][4] = {};

  // per-lane source offset: row (lane>>3), 16B group swizzled by row&7 (pre-swizzled source
  // + linear gll dest + swizzled ds_read = the proven conflict-free scheme from gemm_bt)
  const size_t loff = (size_t)(lane >> 3) * K + (size_t)(((lane & 7) ^ (lane >> 3)) << 3);
  const u16* Abase = A + (size_t)(bm * 256) * K + loff;
  const u16* Bbase = Bw + (size_t)(bn * 256) * K + loff;

  auto stageA = [&](int buf, int kt, int h) {
#pragma unroll
    for (int i = 0; i < 2; ++i) {
      const int c = wave * 2 + i;                       // chunk 0..15, 8 rows each
      const int rb = ((c & 8) << 4) | (h * 64 + (c & 7) * 8);
      gll16(Abase + (size_t)rb * K + kt * 64, &As[buf][rb * 64]);
    }
  };
  auto stageB = [&](int buf, int kt, int h) {
#pragma unroll
    for (int i = 0; i < 2; ++i) {
      const int c = wave * 2 + i;
      const int rb = (c >> 2) * 64 + h * 32 + (c & 3) * 8;
      gll16(Bbase + (size_t)rb * K + kt * 64, &Bs[buf][rb * 64]);
    }
  };

  const int nk = K >> 6;
  // prologue: tile 0 fully staged (A0,B0,A1,B1); wait A0,B0 landed (A1,B1 stay in flight)
  stageA(0, 0, 0); stageB(0, 0, 0); stageA(0, 0, 1); stageB(0, 0, 1);
  asm volatile("s_waitcnt vmcnt(4)" ::: "memory");
  __builtin_amdgcn_sched_barrier(0);
  __builtin_amdgcn_s_barrier();

  for (int kt = 0; kt < nk; ++kt) {
    const int cb = kt & 1, ob = cb ^ 1;
    const u16* as = As[cb];
    const u16* bs = Bs[cb];
    const bool pf = (kt + 1 < nk);
    PHASE256(0, 0, { if (pf) stageA(ob, kt + 1, 0); }, 1);  // wait: A1(cur) landed
    PHASE256(1, 0, { if (pf) stageB(ob, kt + 1, 0); }, 1);  // wait: B1(cur) landed
    PHASE256(1, 1, { if (pf) stageA(ob, kt + 1, 1); }, 0);  // nothing new needed next phase
    PHASE256(0, 1, { if (pf) stageB(ob, kt + 1, 1); }, 1);  // wait: A0,B0(next) landed
  }

#pragma unroll
  for (int i = 0; i < 8; ++i) {
    const int row0 = bm * 256 + wm * 128 + (i >> 2) * 64 + (i & 3) * 16 + quad * 4;
#pragma unroll
    for (int j = 0; j < 4; ++j) {
      const int col = bn * 256 + wn * 64 + (j >> 1) * 32 + (j & 1) * 16 + l15;
      const float bv = bias[col];
#pragma unroll
      for (int r = 0; r < 4; ++r) {
        const size_t idx = (size_t)(row0 + r) * N + col;
        float v = acc[i][j][r] + bv;
        if constexpr (MODE == 0) {
          ((u16*)Cout)[idx] = f2bf(v);
        } else {
          v = 0.5f * v * (1.0f + erff(v * 0.70710678118654752f));
          ((u16*)Cout)[idx] = f2bf(v);
        }
      }
    }
  }
}

// ---------------- RoPE: qkv [B,S,NH*3D] -> Qr/Kr [B,NH,S,D] ----------------
__global__ __launch_bounds__(256) void rope_kernel(const u16* __restrict__ qkv,
                                                   u16* __restrict__ Qr,
                                                   u16* __restrict__ Kr) {
  const int tid = threadIdx.x;
  const int d = tid & 63;
  const int s = blockIdx.x * 4 + (tid >> 6);
  const int h = blockIdx.y, b = blockIdx.z;
  const u16* row = qkv + ((size_t)(b * SS + s)) * (3 * HH) + h * (3 * DD);
  const float q1 = b2f(row[d]),        q2 = b2f(row[d + 64]);
  const float k1 = b2f(row[DD + d]),   k2 = b2f(row[DD + d + 64]);
  const float inv = expf((float)d * -0.14391156830963714f);
  const float ang = (float)s * inv;
  const float cs = cosf(ang), sn = sinf(ang);
  const size_t o = ((size_t)(b * NHH + h) * SS + s) * DD;
  Qr[o + d]      = f2bf(q1 * cs - q2 * sn);
  Qr[o + d + 64] = f2bf(q2 * cs + q1 * sn);
  Kr[o + d]      = f2bf(k1 * cs - k2 * sn);
  Kr[o + d + 64] = f2bf(k2 * cs + k1 * sn);
}

// ---------------- V transpose: qkv V-slice -> Vt_g [B*NH, D, S] ----------------
__device__ __forceinline__ int vslot(int s, int chunk) {
  return chunk ^ (s & 7) ^ ((s >> 3) & 7);
}
__global__ __launch_bounds__(256) void vtrans(const u16* __restrict__ qkv,
                                              u16* __restrict__ Vt) {
  __shared__ __align__(16) u16 Vs[64 * 128];
  const int tid = threadIdx.x;
  const int s0 = blockIdx.x * 64;
  const int bh = blockIdx.y;
  const int b = bh >> 4, h = bh & 15;
  const u16* src = qkv + (size_t)(b * SS + s0) * (3 * HH) + h * (3 * DD) + 2 * DD;
#pragma unroll
  for (int rr = 0; rr < 4; ++rr) {
    const int task = tid + rr * 256;
    const int sr = task >> 4, c = task & 15;
    u16x8 v = *(const u16x8*)(src + (size_t)sr * (3 * HH) + c * 8);
    const int sl = (vslot(sr, c & 7) | (c & 8));
    *(u16x8*)&Vs[sr * 128 + sl * 8] = v;
  }
  __syncthreads();
#pragma unroll
  for (int rr = 0; rr < 4; ++rr) {
    const int task = tid + rr * 256;
    const int dr = task >> 3, c = task & 7;
    u16x8 o;
#pragma unroll
    for (int e = 0; e < 8; ++e) {
      const int s = c * 8 + e;
      const int sl = (vslot(s, dr >> 3 & 7) | ((dr >> 3) & 8));
      o[e] = Vs[s * 128 + sl * 8 + (dr & 7)];
    }
    *(u16x8*)(Vt + (size_t)(bh * DD + dr) * SS + s0 + c * 8) = o;
  }
}

// ---------------- causal flash attention, paired q-tiles, dbuf K/V^T ----------------
__device__ __forceinline__ void softmax_pv(f32x4 s4[4], bool diag, int qrl0,
                                           float m_run[4], float l_run[4],
                                           f32x4 oacc[8], const u16* vtb,
                                           u16* psw, int quad, int l15) {
  const float SCL = 0.12751742904630190f;  // (1/sqrt(128)) * log2(e)
  float pv[4][4];
  float mx[4] = {-3e38f, -3e38f, -3e38f, -3e38f};
#pragma unroll
  for (int jt = 0; jt < 4; ++jt)
#pragma unroll
    for (int r = 0; r < 4; ++r) {
      float sv = s4[jt][r] * SCL;
      if (diag && (jt * 16 + l15) > (qrl0 + r)) sv = -3e38f;
      pv[jt][r] = sv;
      mx[r] = fmaxf(mx[r], sv);
    }
#pragma unroll
  for (int r = 0; r < 4; ++r) {
    mx[r] = fmaxf(mx[r], __shfl_xor(mx[r], 1));
    mx[r] = fmaxf(mx[r], __shfl_xor(mx[r], 2));
    mx[r] = fmaxf(mx[r], __shfl_xor(mx[r], 4));
    mx[r] = fmaxf(mx[r], __shfl_xor(mx[r], 8));
  }
  float al[4];
#pragma unroll
  for (int r = 0; r < 4; ++r) {
    const float mnew = fmaxf(m_run[r], mx[r]);
    al[r] = exp2f(m_run[r] - mnew);
    m_run[r] = mnew;
  }
  float rs[4] = {0.f, 0.f, 0.f, 0.f};
#pragma unroll
  for (int jt = 0; jt < 4; ++jt)
#pragma unroll
    for (int r = 0; r < 4; ++r) {
      const float pp = exp2f(pv[jt][r] - m_run[r]);
      pv[jt][r] = pp;
      rs[r] += pp;
    }
#pragma unroll
  for (int r = 0; r < 4; ++r) {
    rs[r] += __shfl_xor(rs[r], 1);
    rs[r] += __shfl_xor(rs[r], 2);
    rs[r] += __shfl_xor(rs[r], 4);
    rs[r] += __shfl_xor(rs[r], 8);
    l_run[r] = l_run[r] * al[r] + rs[r];
  }
#pragma unroll
  for (int jn = 0; jn < 8; ++jn)
#pragma unroll
    for (int r = 0; r < 4; ++r) oacc[jn][r] *= al[r];
#pragma unroll
  for (int jt = 0; jt < 4; ++jt)
#pragma unroll
    for (int r = 0; r < 4; ++r) {
      const int qr = quad * 4 + r, key = jt * 16 + l15;
      psw[qr * 64 + (((key >> 3) ^ (qr & 7)) << 3) + (key & 7)] = f2bf(pv[jt][r]);
    }
  __threadfence_block();
#pragma unroll
  for (int t = 0; t < 2; ++t) {
    const int gg = t * 4 + quad;
    bf16x8 pf = *(const bf16x8*)&psw[l15 * 64 + ((gg ^ (l15 & 7)) << 3)];
#pragma unroll
    for (int jn = 0; jn < 8; ++jn) {
      const int nd = jn * 16 + l15;
      bf16x8 vf = *(const bf16x8*)&vtb[nd * 64 + ((gg ^ (nd & 7)) << 3)];
      oacc[jn] = __builtin_amdgcn_mfma_f32_16x16x32_bf16(pf, vf, oacc[jn], 0, 0, 0);
    }
  }
}

__global__ __launch_bounds__(256, 2) void attn_kernel(const u16* __restrict__ Q,
                                                      const u16* __restrict__ Kg,
                                                      const u16* __restrict__ Vtg,
                                                      u16* __restrict__ ctx) {
  __shared__ __align__(16) u16 Ks[2][64 * 128];
  __shared__ __align__(16) u16 Vt[2][128 * 64];
  __shared__ __align__(16) u16 Ps[4][16 * 64];
  const int tid = threadIdx.x;
  const int wave = tid >> 6, lane = tid & 63;
  const int l15 = lane & 15, quad = lane >> 4;
  const int p = blockIdx.x, h = blockIdx.y, b = blockIdx.z;
  const int qlo = p, qhi = 31 - p;
  const size_t bh = (size_t)(b * NHH + h);
  const u16* Qp = Q + bh * ((size_t)SS * DD);
  const u16* Kp = Kg + bh * ((size_t)SS * DD);
  const u16* Vp = Vtg + bh * ((size_t)DD * SS);

  bf16x8 qfl[4], qfh[4];
  {
    const u16* ql = Qp + (size_t)(qlo * 64 + wave * 16 + l15) * DD + quad * 8;
    const u16* qh = Qp + (size_t)(qhi * 64 + wave * 16 + l15) * DD + quad * 8;
#pragma unroll
    for (int t = 0; t < 4; ++t) {
      qfl[t] = *(const bf16x8*)(ql + t * 32);
      qfh[t] = *(const bf16x8*)(qh + t * 32);
    }
  }

  f32x4 oal[8] = {}, oah[8] = {};
  float ml[4] = {-3e38f, -3e38f, -3e38f, -3e38f};
  float mh[4] = {-3e38f, -3e38f, -3e38f, -3e38f};
  float ll[4] = {0.f, 0.f, 0.f, 0.f}, lh[4] = {0.f, 0.f, 0.f, 0.f};

  auto stage = [&](int kt, int bufi) {
    const int k0 = kt * 64;
#pragma unroll
    for (int i = 0; i < 4; ++i) {
      const int g = wave * 4 + i;
      const int r = g * 4 + quad;
      const int c = l15 ^ (r & 15);
      gll16(Kp + (size_t)(k0 + r) * DD + c * 8, &Ks[bufi][g * 512]);
    }
#pragma unroll
    for (int i = 0; i < 4; ++i) {
      const int g = wave * 4 + i;
      const int d = g * 8 + (lane >> 3);
      const int c = (lane & 7) ^ (d & 7);
      gll16(Vp + (size_t)d * SS + k0 + c * 8, &Vt[bufi][g * 512]);
    }
  };

  stage(0, 0);
  const int qrl0 = wave * 16 + quad * 4;
  for (int kt = 0; kt <= qhi; ++kt) {
    __syncthreads();
    const u16* ksb = Ks[kt & 1];
    const u16* vtb = Vt[kt & 1];
    if (kt < qhi) stage(kt + 1, (kt + 1) & 1);
    const bool lo = (kt <= qlo);

    f32x4 sh4[4] = {}, sl4[4] = {};
#pragma unroll
    for (int t = 0; t < 4; ++t)
#pragma unroll
      for (int jt = 0; jt < 4; ++jt) {
        const int key = jt * 16 + l15;
        bf16x8 kf = *(const bf16x8*)&ksb[key * 128 + (((t * 4 + quad) ^ (key & 15)) << 3)];
        sh4[jt] = __builtin_amdgcn_mfma_f32_16x16x32_bf16(qfh[t], kf, sh4[jt], 0, 0, 0);
        if (lo) sl4[jt] = __builtin_amdgcn_mfma_f32_16x16x32_bf16(qfl[t], kf, sl4[jt], 0, 0, 0);
      }

    softmax_pv(sh4, kt == qhi, qrl0, mh, lh, oah, vtb, Ps[wave], quad, l15);
    if (lo) softmax_pv(sl4, kt == qlo, qrl0, ml, ll, oal, vtb, Ps[wave], quad, l15);
  }

  float invh[4], invl[4];
#pragma unroll
  for (int r = 0; r < 4; ++r) { invh[r] = 1.0f / lh[r]; invl[r] = 1.0f / ll[r]; }
#pragma unroll
  for (int jn = 0; jn < 8; ++jn)
#pragma unroll
    for (int r = 0; r < 4; ++r) {
      const int col = h * DD + jn * 16 + l15;
      const int rh = qhi * 64 + qrl0 + r;
      const int rl = qlo * 64 + qrl0 + r;
      ctx[(size_t)(b * SS + rh) * HH + col] = f2bf(oah[jn][r] * invh[r]);
      ctx[(size_t)(b * SS + rl) * HH + col] = f2bf(oal[jn][r] * invl[r]);
    }
}

// ---------------- launch ----------------
extern "C" void kernel_launch(void* const* d_in, const int* in_sizes, int n_in,
                              void* d_out, int out_size, void* d_ws, size_t ws_size,
                              hipStream_t stream) {
  (void)in_sizes; (void)n_in; (void)ws_size;
  const float* hidden = (const float*)d_in[0];
  const float* ln1w = (const float*)d_in[2];
  const float* ln1b = (const float*)d_in[3];
  const float* wqkv = (const float*)d_in[4];
  const float* bqkv = (const float*)d_in[5];
  const float* wdense = (const float*)d_in[6];
  const float* bdense = (const float*)d_in[7];
  const float* ln2w = (const float*)d_in[8];
  const float* ln2b = (const float*)d_in[9];
  const float* w1 = (const float*)d_in[10];
  const float* b1 = (const float*)d_in[11];
  const float* w2 = (const float*)d_in[12];
  const float* b2 = (const float*)d_in[13];

  char* ws = (char*)d_ws;
  size_t off = 0;
  auto alloc = [&](size_t elems) {
    u16* p = (u16*)(ws + off);
    off += ((elems * 2 + 255) & ~(size_t)255);
    return p;
  };
  u16* wqkvbf = alloc((size_t)3 * HH * HH);
  u16* wdbf   = alloc((size_t)HH * HH);
  u16* w1bf   = alloc((size_t)FFF * HH);
  u16* w2bf   = alloc((size_t)HH * FFF);
  u16* xbf    = alloc((size_t)MM * HH);
  u16* ctx    = alloc((size_t)MM * HH);
  u16* big    = alloc((size_t)MM * 3 * HH + 3 * (size_t)BB * NHH * SS * DD);
  u16* qkvbuf = big;
  u16* Qr = big + (size_t)MM * 3 * HH;
  u16* Kr = Qr + (size_t)BB * NHH * SS * DD;
  u16* Vtg = Kr + (size_t)BB * NHH * SS * DD;
  u16* inter = big;                              // aliases qkv+Qr (dead by FF1)

  CvtArgs ca;
  ca.src[0] = wqkv;   ca.dst[0] = wqkvbf; ca.n[0] = 3 * HH * HH;
  ca.src[1] = wdense; ca.dst[1] = wdbf;   ca.n[1] = HH * HH;
  ca.src[2] = w1;     ca.dst[2] = w1bf;   ca.n[2] = FFF * HH;
  ca.src[3] = w2;     ca.dst[3] = w2bf;   ca.n[3] = HH * FFF;
  cvt_all<<<dim3((FFF * HH) / 1024, 4), 256, 0, stream>>>(ca);

  ln_bf16<<<MM, 256, 0, stream>>>(hidden, ln1w, ln1b, xbf);
  gemm256<0><<<dim3(MM / 256, (3 * HH) / 256), 512, 0, stream>>>(
      xbf, wqkvbf, bqkv, qkvbuf, MM, 3 * HH, HH);
  rope_kernel<<<dim3(SS / 4, NHH, BB), 256, 0, stream>>>(qkvbuf, Qr, Kr);
  vtrans<<<dim3(SS / 64, BB * NHH), 256, 0, stream>>>(qkvbuf, Vtg);
  attn_kernel<<<dim3(16, NHH, BB), 256, 0, stream>>>(Qr, Kr, Vtg, ctx);
  gemm_bt<1, 1><<<dim3(MM / 128, HH / 128), 256, 0, stream>>>(
      ctx, wdbf, bdense, hidden, d_out, MM, HH, HH);
  ln_bf16<<<MM, 256, 0, stream>>>((const float*)d_out, ln2w, ln2b, xbf);
  gemm256<2><<<dim3(MM / 256, FFF / 256), 512, 0, stream>>>(
      xbf, w1bf, b1, inter, MM, FFF, HH);
  gemm_bt<1, 1><<<dim3(MM / 128, HH / 128), 256, 0, stream>>>(
      inter, w2bf, b2, (const float*)d_out, d_out, MM, HH, FFF);

  const size_t hid_elems = (size_t)MM * HH;
  if ((size_t)out_size > hid_elems)
    hipMemsetAsync((char*)d_out + hid_elems * 4, 0,
                   ((size_t)out_size - hid_elems) * 4, stream);
}

// Round 2
// 915.251 us; speedup vs baseline: 1.1537x; 1.1537x over previous
//
#include <hip/hip_runtime.h>
#include <math.h>

typedef unsigned short u16;
typedef unsigned int u32;
typedef __attribute__((ext_vector_type(8))) __bf16 bf16x8;
typedef __attribute__((ext_vector_type(4))) float f32x4;
typedef __attribute__((ext_vector_type(8))) u16 u16x8;
typedef __attribute__((ext_vector_type(4))) u16 u16x4;

#define BB 2
#define SS 2048
#define HH 2048
#define NHH 16
#define DD 128
#define FFF 8192
#define MM (BB * SS)

__device__ __forceinline__ u16 f2bf(float f) {
  u32 u = __float_as_uint(f);
  u32 r = (u + 0x7FFFu + ((u >> 16) & 1u)) >> 16;
  return (u16)r;
}
__device__ __forceinline__ float b2f(u16 h) {
  return __uint_as_float(((u32)h) << 16);
}
__device__ __forceinline__ void gll16(const void* g, void* l) {
  __builtin_amdgcn_global_load_lds((const __attribute__((address_space(1))) void*)g,
                                   (__attribute__((address_space(3))) void*)l, 16, 0, 0);
}

// ---------------- batched fp32 -> bf16 convert (all 4 weight mats, 1 launch) ----------------
struct CvtArgs {
  const float* src[4];
  u16* dst[4];
  int n[4];
};
__global__ __launch_bounds__(256) void cvt_all(CvtArgs a) {
  const int seg = blockIdx.y;
  const int i = (blockIdx.x * 256 + threadIdx.x) * 4;
  if (i + 3 < a.n[seg]) {
    f32x4 v = *(const f32x4*)(a.src[seg] + i);
    u16x4 o;
    o[0] = f2bf(v[0]); o[1] = f2bf(v[1]); o[2] = f2bf(v[2]); o[3] = f2bf(v[3]);
    *(u16x4*)(a.dst[seg] + i) = o;
  }
}

// ---------------- LayerNorm (fp32 in, bf16 out) ----------------
__global__ __launch_bounds__(256) void ln_bf16(const float* __restrict__ x,
                                               const float* __restrict__ w,
                                               const float* __restrict__ bsh,
                                               u16* __restrict__ out) {
  const int row = blockIdx.x, tid = threadIdx.x;
  const float* xr = x + (size_t)row * HH;
  f32x4 a = ((const f32x4*)xr)[tid * 2];
  f32x4 b = ((const f32x4*)xr)[tid * 2 + 1];
  float s = a[0] + a[1] + a[2] + a[3] + b[0] + b[1] + b[2] + b[3];
  float q = a[0]*a[0] + a[1]*a[1] + a[2]*a[2] + a[3]*a[3]
          + b[0]*b[0] + b[1]*b[1] + b[2]*b[2] + b[3]*b[3];
#pragma unroll
  for (int off = 32; off > 0; off >>= 1) {
    s += __shfl_down(s, off);
    q += __shfl_down(q, off);
  }
  __shared__ float red[8];
  const int wave = tid >> 6;
  if ((tid & 63) == 0) { red[wave] = s; red[4 + wave] = q; }
  __syncthreads();
  s = red[0] + red[1] + red[2] + red[3];
  q = red[4] + red[5] + red[6] + red[7];
  const float mean = s * (1.0f / HH);
  const float var = q * (1.0f / HH) - mean * mean;
  const float rstd = 1.0f / sqrtf(var + 1e-5f);
  f32x4 w0 = ((const f32x4*)w)[tid * 2];
  f32x4 w1 = ((const f32x4*)w)[tid * 2 + 1];
  f32x4 b0 = ((const f32x4*)bsh)[tid * 2];
  f32x4 b1 = ((const f32x4*)bsh)[tid * 2 + 1];
  u16x8 o;
#pragma unroll
  for (int i = 0; i < 4; ++i) o[i] = f2bf((a[i] - mean) * rstd * w0[i] + b0[i]);
#pragma unroll
  for (int i = 0; i < 4; ++i) o[4 + i] = f2bf((b[i] - mean) * rstd * w1[i] + b1[i]);
  *(u16x8*)(out + (size_t)row * HH + tid * 8) = o;
}

// ---------------- GEMM 128x128 (kept for N=2048 GEMMs: grid stays 512 blocks) ----------------
// MODE 0: +bias -> bf16.  MODE 1: +bias+resid(f32) -> f32.  MODE 2: +bias, gelu -> bf16.
template <int MODE, int DB>
__global__ __launch_bounds__(256) void gemm_bt(const u16* __restrict__ A,
                                               const u16* __restrict__ Bw,
                                               const float* __restrict__ bias,
                                               const float* resid, void* Cout,
                                               int M, int N, int K) {
  __shared__ __align__(16) u16 As[DB ? 2 : 1][128 * 64];
  __shared__ __align__(16) u16 Bs[DB ? 2 : 1][128 * 64];
  const int tid = threadIdx.x;
  const int wave = tid >> 6, lane = tid & 63;
  const int l15 = lane & 15, quad = lane >> 4;
  const int bm = blockIdx.x, bn = blockIdx.y;
  const int wm = (wave >> 1) << 6, wn = (wave & 1) << 6;

  f32x4 acc[4][4] = {};

  const int srow = (wave << 5) + (lane >> 3);
  const int sg = (lane & 7) ^ (lane >> 3);
  const u16* aptr = A + (size_t)(bm * 128 + srow) * K + sg * 8;
  const u16* bptr = Bw + (size_t)(bn * 128 + srow) * K + sg * 8;

  auto stage = [&](int buf) {
#pragma unroll
    for (int i = 0; i < 4; ++i)
      gll16(aptr + (size_t)i * 8 * K, &As[buf][(wave * 4 + i) * 512]);
#pragma unroll
    for (int i = 0; i < 4; ++i)
      gll16(bptr + (size_t)i * 8 * K, &Bs[buf][(wave * 4 + i) * 512]);
    aptr += 64; bptr += 64;
  };

  auto compute = [&](int buf) {
#pragma unroll
    for (int tt = 0; tt < 2; ++tt) {
      bf16x8 af[4], bfv[4];
#pragma unroll
      for (int i = 0; i < 4; ++i) {
        const int m = wm + i * 16 + l15;
        const int n = wn + i * 16 + l15;
        const int gi = tt * 4 + quad;
        af[i] = *(const bf16x8*)&As[buf][m * 64 + ((gi ^ (m & 7)) << 3)];
        bfv[i] = *(const bf16x8*)&Bs[buf][n * 64 + ((gi ^ (n & 7)) << 3)];
      }
#pragma unroll
      for (int i = 0; i < 4; ++i)
#pragma unroll
        for (int j = 0; j < 4; ++j)
          acc[i][j] = __builtin_amdgcn_mfma_f32_16x16x32_bf16(af[i], bfv[j], acc[i][j], 0, 0, 0);
    }
  };

  const int nk = K >> 6;
  if constexpr (DB) {
    stage(0);
    for (int kt = 0; kt < nk; ++kt) {
      __syncthreads();
      if (kt + 1 < nk) stage((kt + 1) & 1);
      compute(kt & 1);
    }
  } else {
    for (int kt = 0; kt < nk; ++kt) {
      stage(0);
      __syncthreads();
      compute(0);
      __syncthreads();
    }
  }

#pragma unroll
  for (int i = 0; i < 4; ++i) {
    const int row0 = bm * 128 + wm + i * 16 + quad * 4;
#pragma unroll
    for (int j = 0; j < 4; ++j) {
      const int col = bn * 128 + wn + j * 16 + l15;
      const float bv = bias[col];
#pragma unroll
      for (int r = 0; r < 4; ++r) {
        const size_t idx = (size_t)(row0 + r) * N + col;
        float v = acc[i][j][r] + bv;
        if constexpr (MODE == 0) {
          ((u16*)Cout)[idx] = f2bf(v);
        } else if constexpr (MODE == 1) {
          ((float*)Cout)[idx] = v + resid[idx];
        } else {
          v = 0.5f * v * (1.0f + erff(v * 0.70710678118654752f));
          ((u16*)Cout)[idx] = f2bf(v);
        }
      }
    }
  }
}

// ---------------- GEMM 256x256 v2: 3-phase, fragment-reuse, counted-vmcnt schedule ----------
// r1 post-mortem: v1 (4 phases, 2 barriers/phase, 48 ds_read/wave/tile) measured 21% MfmaUtil;
// exposed-LDS model matched (LDS served while MFMA idle, lockstep).  v2 changes:
//  - fragment reuse across quadrant phases: 24 ds_read_b128/wave/K-tile (P1:12, P2:8, P34:4),
//    a0 held in regs P1->P4 (quadrant order (0,0)(1,0)(1,1)(0,1))
//  - ONE barrier per phase (end-of-phase {vmcnt;barrier} fence is the only hazard point);
//    waves skew inside the phase -> one wave's ds_reads served under the other's MFMA
//  - no explicit lgkmcnt: compiler emits fine-grained waits per MFMA operand
//  - counted vmcnt: P1-end retires A1(cur), P2-end retires B1(cur), P34-end retires A0',B0';
//    never drains to 0 in steady state (last tile: vmcnt 2/0 peel).
// Hazards: stage(kt+1) writes buffer read in kt — every region's last read completes >= 1
// phase-fence before its overwriting stage issues; reads of staged data covered by the
// issuing waves' vmcnt + barrier one phase earlier.  A-half h = rows {h*64..} u {128+h*64..};
// B-half h = rows {q*64+h*32..+31}.
template <int MODE>
__global__ __launch_bounds__(512, 2) void gemm256(const u16* __restrict__ A,
                                                  const u16* __restrict__ Bw,
                                                  const float* __restrict__ bias,
                                                  void* Cout, int M, int N, int K) {
  __shared__ __align__(16) u16 As[2][256 * 64];
  __shared__ __align__(16) u16 Bs[2][256 * 64];
  const int tid = threadIdx.x;
  const int wave = tid >> 6, lane = tid & 63;
  const int l15 = lane & 15, quad = lane >> 4;
  const int wm = wave >> 2, wn = wave & 3;
  const int bm = blockIdx.x, bn = blockIdx.y;

  f32x4 acc[8][4] = {};

  // per-lane source offset: row (lane>>3), 16B group swizzled by row&7 (pre-swizzled source
  // + linear gll dest + swizzled ds_read = proven conflict-free: 0 bank conflicts measured)
  const size_t loff = (size_t)(lane >> 3) * K + (size_t)(((lane & 7) ^ (lane >> 3)) << 3);
  const u16* Abase = A + (size_t)(bm * 256) * K + loff;
  const u16* Bbase = Bw + (size_t)(bn * 256) * K + loff;

  auto stageA = [&](int buf, int kt, int h) {
#pragma unroll
    for (int i = 0; i < 2; ++i) {
      const int c = wave * 2 + i;                       // chunk 0..15, 8 rows each
      const int rb = ((c & 8) << 4) | (h * 64 + (c & 7) * 8);
      gll16(Abase + (size_t)rb * K + kt * 64, &As[buf][rb * 64]);
    }
  };
  auto stageB = [&](int buf, int kt, int h) {
#pragma unroll
    for (int i = 0; i < 2; ++i) {
      const int c = wave * 2 + i;
      const int rb = (c >> 2) * 64 + h * 32 + (c & 3) * 8;
      gll16(Bbase + (size_t)rb * K + kt * 64, &Bs[buf][rb * 64]);
    }
  };

  auto ldA = [&](const u16* as_, int qm, bf16x8 (&dst)[4][2]) {
#pragma unroll
    for (int im = 0; im < 4; ++im) {
      const int ar = wm * 128 + qm * 64 + im * 16 + l15;
#pragma unroll
      for (int tt = 0; tt < 2; ++tt)
        dst[im][tt] = *(const bf16x8*)&as_[ar * 64 + ((((tt << 2) + quad) ^ (ar & 7)) << 3)];
    }
  };
  auto ldB = [&](const u16* bs_, int qn, bf16x8 (&dst)[2][2]) {
#pragma unroll
    for (int jn = 0; jn < 2; ++jn) {
      const int br = wn * 64 + qn * 32 + jn * 16 + l15;
#pragma unroll
      for (int tt = 0; tt < 2; ++tt)
        dst[jn][tt] = *(const bf16x8*)&bs_[br * 64 + ((((tt << 2) + quad) ^ (br & 7)) << 3)];
    }
  };
  auto mm = [&](bf16x8 (&a)[4][2], bf16x8 (&b)[2][2], int i0, int j0) {
    __builtin_amdgcn_s_setprio(1);
#pragma unroll
    for (int tt = 0; tt < 2; ++tt)
#pragma unroll
      for (int im = 0; im < 4; ++im)
#pragma unroll
        for (int jn = 0; jn < 2; ++jn)
          acc[i0 + im][j0 + jn] = __builtin_amdgcn_mfma_f32_16x16x32_bf16(
              a[im][tt], b[jn][tt], acc[i0 + im][j0 + jn], 0, 0, 0);
    __builtin_amdgcn_s_setprio(0);
  };

  const int nk = K >> 6;
  // prologue: stage tile 0 fully; wait A0,B0 landed (A1,B1 stay in flight = steady state)
  stageA(0, 0, 0); stageB(0, 0, 0); stageA(0, 0, 1); stageB(0, 0, 1);
  asm volatile("s_waitcnt vmcnt(4)" ::: "memory");
  __builtin_amdgcn_sched_barrier(0);
  __builtin_amdgcn_s_barrier();

  for (int kt = 0; kt < nk; ++kt) {
    const int cb = kt & 1, ob = cb ^ 1;
    const u16* as_ = As[cb];
    const u16* bs_ = Bs[cb];
    const bool pf = (kt + 1 < nk);
    bf16x8 a0[4][2], a1[4][2], b0[2][2], b1[2][2];

    // P1: quadrant (0,0).  outstanding in: [A1cur,B1cur]
    ldA(as_, 0, a0);
    ldB(bs_, 0, b0);
    if (pf) stageA(ob, kt + 1, 0);
    mm(a0, b0, 0, 0);
    if (pf) asm volatile("s_waitcnt vmcnt(4)" ::: "memory");  // retire A1cur
    else    asm volatile("s_waitcnt vmcnt(2)" ::: "memory");
    __builtin_amdgcn_sched_barrier(0);
    __builtin_amdgcn_s_barrier();

    // P2: quadrant (1,0), reuse b0.
    ldA(as_, 1, a1);
    if (pf) stageB(ob, kt + 1, 0);
    mm(a1, b0, 4, 0);
    if (pf) asm volatile("s_waitcnt vmcnt(4)" ::: "memory");  // retire B1cur
    else    asm volatile("s_waitcnt vmcnt(0)" ::: "memory");
    __builtin_amdgcn_sched_barrier(0);
    __builtin_amdgcn_s_barrier();

    // P3+P4: quadrants (1,1) and (0,1), reuse a1 then a0 (held since P1).
    ldB(bs_, 1, b1);
    if (pf) stageA(ob, kt + 1, 1);
    mm(a1, b1, 4, 2);
    if (pf) stageB(ob, kt + 1, 1);
    mm(a0, b1, 0, 2);
    if (pf) {
      asm volatile("s_waitcnt vmcnt(4)" ::: "memory");        // retire A0',B0'
      __builtin_amdgcn_sched_barrier(0);
    }
    __builtin_amdgcn_s_barrier();
  }

#pragma unroll
  for (int i = 0; i < 8; ++i) {
    const int row0 = bm * 256 + wm * 128 + i * 16 + quad * 4;
#pragma unroll
    for (int j = 0; j < 4; ++j) {
      const int col = bn * 256 + wn * 64 + j * 16 + l15;
      const float bv = bias[col];
#pragma unroll
      for (int r = 0; r < 4; ++r) {
        const size_t idx = (size_t)(row0 + r) * N + col;
        float v = acc[i][j][r] + bv;
        if constexpr (MODE == 0) {
          ((u16*)Cout)[idx] = f2bf(v);
        } else {
          v = 0.5f * v * (1.0f + erff(v * 0.70710678118654752f));
          ((u16*)Cout)[idx] = f2bf(v);
        }
      }
    }
  }
}

// ---------------- RoPE: qkv [B,S,NH*3D] -> Qr/Kr [B,NH,S,D] ----------------
__global__ __launch_bounds__(256) void rope_kernel(const u16* __restrict__ qkv,
                                                   u16* __restrict__ Qr,
                                                   u16* __restrict__ Kr) {
  const int tid = threadIdx.x;
  const int d = tid & 63;
  const int s = blockIdx.x * 4 + (tid >> 6);
  const int h = blockIdx.y, b = blockIdx.z;
  const u16* row = qkv + ((size_t)(b * SS + s)) * (3 * HH) + h * (3 * DD);
  const float q1 = b2f(row[d]),        q2 = b2f(row[d + 64]);
  const float k1 = b2f(row[DD + d]),   k2 = b2f(row[DD + d + 64]);
  const float inv = expf((float)d * -0.14391156830963714f);
  const float ang = (float)s * inv;
  const float cs = cosf(ang), sn = sinf(ang);
  const size_t o = ((size_t)(b * NHH + h) * SS + s) * DD;
  Qr[o + d]      = f2bf(q1 * cs - q2 * sn);
  Qr[o + d + 64] = f2bf(q2 * cs + q1 * sn);
  Kr[o + d]      = f2bf(k1 * cs - k2 * sn);
  Kr[o + d + 64] = f2bf(k2 * cs + k1 * sn);
}

// ---------------- V transpose: qkv V-slice -> Vt_g [B*NH, D, S] ----------------
__device__ __forceinline__ int vslot(int s, int chunk) {
  return chunk ^ (s & 7) ^ ((s >> 3) & 7);
}
__global__ __launch_bounds__(256) void vtrans(const u16* __restrict__ qkv,
                                              u16* __restrict__ Vt) {
  __shared__ __align__(16) u16 Vs[64 * 128];
  const int tid = threadIdx.x;
  const int s0 = blockIdx.x * 64;
  const int bh = blockIdx.y;
  const int b = bh >> 4, h = bh & 15;
  const u16* src = qkv + (size_t)(b * SS + s0) * (3 * HH) + h * (3 * DD) + 2 * DD;
#pragma unroll
  for (int rr = 0; rr < 4; ++rr) {
    const int task = tid + rr * 256;
    const int sr = task >> 4, c = task & 15;
    u16x8 v = *(const u16x8*)(src + (size_t)sr * (3 * HH) + c * 8);
    const int sl = (vslot(sr, c & 7) | (c & 8));
    *(u16x8*)&Vs[sr * 128 + sl * 8] = v;
  }
  __syncthreads();
#pragma unroll
  for (int rr = 0; rr < 4; ++rr) {
    const int task = tid + rr * 256;
    const int dr = task >> 3, c = task & 7;
    u16x8 o;
#pragma unroll
    for (int e = 0; e < 8; ++e) {
      const int s = c * 8 + e;
      const int sl = (vslot(s, dr >> 3 & 7) | ((dr >> 3) & 8));
      o[e] = Vs[s * 128 + sl * 8 + (dr & 7)];
    }
    *(u16x8*)(Vt + (size_t)(bh * DD + dr) * SS + s0 + c * 8) = o;
  }
}

// ---------------- causal flash attention, paired q-tiles, dbuf K/V^T ----------------
__device__ __forceinline__ void softmax_pv(f32x4 s4[4], bool diag, int qrl0,
                                           float m_run[4], float l_run[4],
                                           f32x4 oacc[8], const u16* vtb,
                                           u16* psw, int quad, int l15) {
  const float SCL = 0.12751742904630190f;  // (1/sqrt(128)) * log2(e)
  float pv[4][4];
  float mx[4] = {-3e38f, -3e38f, -3e38f, -3e38f};
#pragma unroll
  for (int jt = 0; jt < 4; ++jt)
#pragma unroll
    for (int r = 0; r < 4; ++r) {
      float sv = s4[jt][r] * SCL;
      if (diag && (jt * 16 + l15) > (qrl0 + r)) sv = -3e38f;
      pv[jt][r] = sv;
      mx[r] = fmaxf(mx[r], sv);
    }
#pragma unroll
  for (int r = 0; r < 4; ++r) {
    mx[r] = fmaxf(mx[r], __shfl_xor(mx[r], 1));
    mx[r] = fmaxf(mx[r], __shfl_xor(mx[r], 2));
    mx[r] = fmaxf(mx[r], __shfl_xor(mx[r], 4));
    mx[r] = fmaxf(mx[r], __shfl_xor(mx[r], 8));
  }
  float al[4];
#pragma unroll
  for (int r = 0; r < 4; ++r) {
    const float mnew = fmaxf(m_run[r], mx[r]);
    al[r] = exp2f(m_run[r] - mnew);
    m_run[r] = mnew;
  }
  float rs[4] = {0.f, 0.f, 0.f, 0.f};
#pragma unroll
  for (int jt = 0; jt < 4; ++jt)
#pragma unroll
    for (int r = 0; r < 4; ++r) {
      const float pp = exp2f(pv[jt][r] - m_run[r]);
      pv[jt][r] = pp;
      rs[r] += pp;
    }
#pragma unroll
  for (int r = 0; r < 4; ++r) {
    rs[r] += __shfl_xor(rs[r], 1);
    rs[r] += __shfl_xor(rs[r], 2);
    rs[r] += __shfl_xor(rs[r], 4);
    rs[r] += __shfl_xor(rs[r], 8);
    l_run[r] = l_run[r] * al[r] + rs[r];
  }
#pragma unroll
  for (int jn = 0; jn < 8; ++jn)
#pragma unroll
    for (int r = 0; r < 4; ++r) oacc[jn][r] *= al[r];
#pragma unroll
  for (int jt = 0; jt < 4; ++jt)
#pragma unroll
    for (int r = 0; r < 4; ++r) {
      const int qr = quad * 4 + r, key = jt * 16 + l15;
      psw[qr * 64 + (((key >> 3) ^ (qr & 7)) << 3) + (key & 7)] = f2bf(pv[jt][r]);
    }
  __threadfence_block();
#pragma unroll
  for (int t = 0; t < 2; ++t) {
    const int gg = t * 4 + quad;
    bf16x8 pf = *(const bf16x8*)&psw[l15 * 64 + ((gg ^ (l15 & 7)) << 3)];
#pragma unroll
    for (int jn = 0; jn < 8; ++jn) {
      const int nd = jn * 16 + l15;
      bf16x8 vf = *(const bf16x8*)&vtb[nd * 64 + ((gg ^ (nd & 7)) << 3)];
      oacc[jn] = __builtin_amdgcn_mfma_f32_16x16x32_bf16(pf, vf, oacc[jn], 0, 0, 0);
    }
  }
}

__global__ __launch_bounds__(256, 2) void attn_kernel(const u16* __restrict__ Q,
                                                      const u16* __restrict__ Kg,
                                                      const u16* __restrict__ Vtg,
                                                      u16* __restrict__ ctx) {
  __shared__ __align__(16) u16 Ks[2][64 * 128];
  __shared__ __align__(16) u16 Vt[2][128 * 64];
  __shared__ __align__(16) u16 Ps[4][16 * 64];
  const int tid = threadIdx.x;
  const int wave = tid >> 6, lane = tid & 63;
  const int l15 = lane & 15, quad = lane >> 4;
  const int p = blockIdx.x, h = blockIdx.y, b = blockIdx.z;
  const int qlo = p, qhi = 31 - p;
  const size_t bh = (size_t)(b * NHH + h);
  const u16* Qp = Q + bh * ((size_t)SS * DD);
  const u16* Kp = Kg + bh * ((size_t)SS * DD);
  const u16* Vp = Vtg + bh * ((size_t)DD * SS);

  bf16x8 qfl[4], qfh[4];
  {
    const u16* ql = Qp + (size_t)(qlo * 64 + wave * 16 + l15) * DD + quad * 8;
    const u16* qh = Qp + (size_t)(qhi * 64 + wave * 16 + l15) * DD + quad * 8;
#pragma unroll
    for (int t = 0; t < 4; ++t) {
      qfl[t] = *(const bf16x8*)(ql + t * 32);
      qfh[t] = *(const bf16x8*)(qh + t * 32);
    }
  }

  f32x4 oal[8] = {}, oah[8] = {};
  float ml[4] = {-3e38f, -3e38f, -3e38f, -3e38f};
  float mh[4] = {-3e38f, -3e38f, -3e38f, -3e38f};
  float ll[4] = {0.f, 0.f, 0.f, 0.f}, lh[4] = {0.f, 0.f, 0.f, 0.f};

  auto stage = [&](int kt, int bufi) {
    const int k0 = kt * 64;
#pragma unroll
    for (int i = 0; i < 4; ++i) {
      const int g = wave * 4 + i;
      const int r = g * 4 + quad;
      const int c = l15 ^ (r & 15);
      gll16(Kp + (size_t)(k0 + r) * DD + c * 8, &Ks[bufi][g * 512]);
    }
#pragma unroll
    for (int i = 0; i < 4; ++i) {
      const int g = wave * 4 + i;
      const int d = g * 8 + (lane >> 3);
      const int c = (lane & 7) ^ (d & 7);
      gll16(Vp + (size_t)d * SS + k0 + c * 8, &Vt[bufi][g * 512]);
    }
  };

  stage(0, 0);
  const int qrl0 = wave * 16 + quad * 4;
  for (int kt = 0; kt <= qhi; ++kt) {
    __syncthreads();
    const u16* ksb = Ks[kt & 1];
    const u16* vtb = Vt[kt & 1];
    if (kt < qhi) stage(kt + 1, (kt + 1) & 1);
    const bool lo = (kt <= qlo);

    f32x4 sh4[4] = {}, sl4[4] = {};
#pragma unroll
    for (int t = 0; t < 4; ++t)
#pragma unroll
      for (int jt = 0; jt < 4; ++jt) {
        const int key = jt * 16 + l15;
        bf16x8 kf = *(const bf16x8*)&ksb[key * 128 + (((t * 4 + quad) ^ (key & 15)) << 3)];
        sh4[jt] = __builtin_amdgcn_mfma_f32_16x16x32_bf16(qfh[t], kf, sh4[jt], 0, 0, 0);
        if (lo) sl4[jt] = __builtin_amdgcn_mfma_f32_16x16x32_bf16(qfl[t], kf, sl4[jt], 0, 0, 0);
      }

    softmax_pv(sh4, kt == qhi, qrl0, mh, lh, oah, vtb, Ps[wave], quad, l15);
    if (lo) softmax_pv(sl4, kt == qlo, qrl0, ml, ll, oal, vtb, Ps[wave], quad, l15);
  }

  float invh[4], invl[4];
#pragma unroll
  for (int r = 0; r < 4; ++r) { invh[r] = 1.0f / lh[r]; invl[r] = 1.0f / ll[r]; }
#pragma unroll
  for (int jn = 0; jn < 8; ++jn)
#pragma unroll
    for (int r = 0; r < 4; ++r) {
      const int col = h * DD + jn * 16 + l15;
      const int rh = qhi * 64 + qrl0 + r;
      const int rl = qlo * 64 + qrl0 + r;
      ctx[(size_t)(b * SS + rh) * HH + col] = f2bf(oah[jn][r] * invh[r]);
      ctx[(size_t)(b * SS + rl) * HH + col] = f2bf(oal[jn][r] * invl[r]);
    }
}

// ---------------- launch ----------------
extern "C" void kernel_launch(void* const* d_in, const int* in_sizes, int n_in,
                              void* d_out, int out_size, void* d_ws, size_t ws_size,
                              hipStream_t stream) {
  (void)in_sizes; (void)n_in; (void)ws_size;
  const float* hidden = (const float*)d_in[0];
  const float* ln1w = (const float*)d_in[2];
  const float* ln1b = (const float*)d_in[3];
  const float* wqkv = (const float*)d_in[4];
  const float* bqkv = (const float*)d_in[5];
  const float* wdense = (const float*)d_in[6];
  const float* bdense = (const float*)d_in[7];
  const float* ln2w = (const float*)d_in[8];
  const float* ln2b = (const float*)d_in[9];
  const float* w1 = (const float*)d_in[10];
  const float* b1 = (const float*)d_in[11];
  const float* w2 = (const float*)d_in[12];
  const float* b2 = (const float*)d_in[13];

  char* ws = (char*)d_ws;
  size_t off = 0;
  auto alloc = [&](size_t elems) {
    u16* p = (u16*)(ws + off);
    off += ((elems * 2 + 255) & ~(size_t)255);
    return p;
  };
  u16* wqkvbf = alloc((size_t)3 * HH * HH);
  u16* wdbf   = alloc((size_t)HH * HH);
  u16* w1bf   = alloc((size_t)FFF * HH);
  u16* w2bf   = alloc((size_t)HH * FFF);
  u16* xbf    = alloc((size_t)MM * HH);
  u16* ctx    = alloc((size_t)MM * HH);
  u16* big    = alloc((size_t)MM * 3 * HH + 3 * (size_t)BB * NHH * SS * DD);
  u16* qkvbuf = big;
  u16* Qr = big + (size_t)MM * 3 * HH;
  u16* Kr = Qr + (size_t)BB * NHH * SS * DD;
  u16* Vtg = Kr + (size_t)BB * NHH * SS * DD;
  u16* inter = big;                              // aliases qkv+Qr (dead by FF1)

  CvtArgs ca;
  ca.src[0] = wqkv;   ca.dst[0] = wqkvbf; ca.n[0] = 3 * HH * HH;
  ca.src[1] = wdense; ca.dst[1] = wdbf;   ca.n[1] = HH * HH;
  ca.src[2] = w1;     ca.dst[2] = w1bf;   ca.n[2] = FFF * HH;
  ca.src[3] = w2;     ca.dst[3] = w2bf;   ca.n[3] = HH * FFF;
  cvt_all<<<dim3((FFF * HH) / 1024, 4), 256, 0, stream>>>(ca);

  ln_bf16<<<MM, 256, 0, stream>>>(hidden, ln1w, ln1b, xbf);
  gemm256<0><<<dim3(MM / 256, (3 * HH) / 256), 512, 0, stream>>>(
      xbf, wqkvbf, bqkv, qkvbuf, MM, 3 * HH, HH);
  rope_kernel<<<dim3(SS / 4, NHH, BB), 256, 0, stream>>>(qkvbuf, Qr, Kr);
  vtrans<<<dim3(SS / 64, BB * NHH), 256, 0, stream>>>(qkvbuf, Vtg);
  attn_kernel<<<dim3(16, NHH, BB), 256, 0, stream>>>(Qr, Kr, Vtg, ctx);
  gemm_bt<1, 1><<<dim3(MM / 128, HH / 128), 256, 0, stream>>>(
      ctx, wdbf, bdense, hidden, d_out, MM, HH, HH);
  ln_bf16<<<MM, 256, 0, stream>>>((const float*)d_out, ln2w, ln2b, xbf);
  gemm256<2><<<dim3(MM / 256, FFF / 256), 512, 0, stream>>>(
      xbf, w1bf, b1, inter, MM, FFF, HH);
  gemm_bt<1, 1><<<dim3(MM / 128, HH / 128), 256, 0, stream>>>(
      inter, w2bf, b2, (const float*)d_out, d_out, MM, HH, FFF);

  const size_t hid_elems = (size_t)MM * HH;
  if ((size_t)out_size > hid_elems)
    hipMemsetAsync((char*)d_out + hid_elems * 4, 0,
                   ((size_t)out_size - hid_elems) * 4, stream);
}